// Round 5
// baseline (49.419 us; speedup 1.0000x reference)
//
#include <hip/hip_runtime.h>

// LIF forward over time-major x: (T=16, B=128, N=16384) fp32.
//   m[t] = 0.5*v[t-1] + x[t];  y[t] = (m >= 1.0);  v[t] = m*(1-y[t])
// R5: one float4 column per thread, but ALL 16 time-plane loads issued
// before any compute (xs[] in registers, static indices), pinned with
// sched_barrier(0) so the scheduler can't sink loads to their uses.
// Goal: 16 outstanding loads/wave -> latency-bound 4.0 TB/s -> ~6 TB/s.

#define LIF_T 16
#define TAU 0.5f
#define VTH 1.0f

typedef float fx4 __attribute__((ext_vector_type(4)));

__global__ __launch_bounds__(256) void lif_fwd_kernel(
    const fx4* __restrict__ x, fx4* __restrict__ y, int cols) {
    int i = blockIdx.x * blockDim.x + threadIdx.x;
    if (i >= cols) return;

    fx4 xs[LIF_T];
    size_t idx = (size_t)i;

    // Issue all 16 loads back-to-back (independent addresses).
#pragma unroll
    for (int t = 0; t < LIF_T; ++t) {
        xs[t] = x[idx + (size_t)t * (size_t)cols];
    }

    // Do not let the scheduler sink loads below this point.
    __builtin_amdgcn_sched_barrier(0);

    fx4 v = {0.0f, 0.0f, 0.0f, 0.0f};
#pragma unroll
    for (int t = 0; t < LIF_T; ++t) {
        fx4 m = v * TAU + xs[t];

        fx4 out;
        out.x = (m.x >= VTH) ? 1.0f : 0.0f;
        out.y = (m.y >= VTH) ? 1.0f : 0.0f;
        out.z = (m.z >= VTH) ? 1.0f : 0.0f;
        out.w = (m.w >= VTH) ? 1.0f : 0.0f;

        v.x = (m.x >= VTH) ? 0.0f : m.x;   // hard reset
        v.y = (m.y >= VTH) ? 0.0f : m.y;
        v.z = (m.z >= VTH) ? 0.0f : m.z;
        v.w = (m.w >= VTH) ? 0.0f : m.w;

        __builtin_nontemporal_store(out, &y[idx + (size_t)t * (size_t)cols]);
    }
}

extern "C" void kernel_launch(void* const* d_in, const int* in_sizes, int n_in,
                              void* d_out, int out_size, void* d_ws, size_t ws_size,
                              hipStream_t stream) {
    const fx4* x = (const fx4*)d_in[0];
    fx4* y = (fx4*)d_out;

    int total = in_sizes[0];
    int cols = total / LIF_T / 4;   // float4 columns per time plane

    const int block = 256;
    int grid = (cols + block - 1) / block;
    lif_fwd_kernel<<<grid, block, 0, stream>>>(x, y, cols);
}